// Round 5
// baseline (217.573 us; speedup 1.0000x reference)
//
#include <hip/hip_runtime.h>
#include <stdint.h>
#include <stddef.h>

// MHA: x[2,2048,1024] -> QKV proj (bf16 MFMA) -> flash attn (H=16, Dh=64) -> out proj.
// R5: attn = barrier-free, LDS-free inner loop. 2048 blocks x 2 waves; each wave owns a
//     KV-half (fixed-base softmax partials are additive -> trivial merge). K and pre-
//     transposed V^T read as MFMA fragments directly from global (L2-resident).

typedef __attribute__((ext_vector_type(8))) short short8;
typedef __attribute__((ext_vector_type(4))) float f32x4;
typedef __attribute__((ext_vector_type(16))) float f32x16;
typedef __attribute__((ext_vector_type(4))) unsigned short u16x4;

#define MFMA16(a, b, c) __builtin_amdgcn_mfma_f32_16x16x32_bf16((a), (b), (c), 0, 0, 0)
#define MFMA32(a, b, c) __builtin_amdgcn_mfma_f32_32x32x16_bf16((a), (b), (c), 0, 0, 0)
#define AS1 __attribute__((address_space(1)))
#define AS3 __attribute__((address_space(3)))

__device__ __forceinline__ unsigned short f2bf(float f) {
  union { float f; unsigned u; } v; v.f = f;
  unsigned r = v.u + 0x7fffu + ((v.u >> 16) & 1u);   // RNE
  return (unsigned short)(r >> 16);
}

__device__ __forceinline__ unsigned cvt_pk_bf16(float lo, float hi) {
  unsigned r;
  asm("v_cvt_pk_bf16_f32 %0, %1, %2" : "=v"(r) : "v"(lo), "v"(hi));
  return r;
}

__device__ __forceinline__ void pl32_swap(unsigned& a, unsigned& b) {
  asm volatile("v_permlane32_swap_b32 %0, %1" : "+v"(a), "+v"(b));
}

__device__ __forceinline__ short8 mk8(unsigned a, unsigned b, unsigned c, unsigned d) {
  union { unsigned u[4]; short8 s; } v;
  v.u[0] = a; v.u[1] = b; v.u[2] = c; v.u[3] = d;
  return v.s;
}

// ---------------- prep ----------------
__global__ __launch_bounds__(256) void cast_x_kernel(const float* __restrict__ x,
                                                     unsigned short* __restrict__ xb) {
  int i = (blockIdx.x * 256 + threadIdx.x) * 4;
  float4 v = *reinterpret_cast<const float4*>(x + i);
  u16x4 o;
  o.x = f2bf(v.x); o.y = f2bf(v.y); o.z = f2bf(v.z); o.w = f2bf(v.w);
  *reinterpret_cast<u16x4*>(xb + i) = o;
}

__global__ __launch_bounds__(256) void prep_w_kernel(const float* __restrict__ wq,
                                                     const float* __restrict__ wk,
                                                     const float* __restrict__ wv,
                                                     const float* __restrict__ wo,
                                                     unsigned short* __restrict__ wt) {
  __shared__ unsigned short t_lds[32][33];
  int bid = blockIdx.x;
  int wsel = bid >> 10;
  int rem = bid & 1023;
  int kb = (rem >> 5) << 5;
  int nb = (rem & 31) << 5;
  const float* W = (wsel == 0) ? wq : (wsel == 1) ? wk : (wsel == 2) ? wv : wo;
  int t = threadIdx.x;
  int r = t >> 3, c = (t & 7) * 4;
  float4 v = *reinterpret_cast<const float4*>(W + (size_t)(kb + r) * 1024 + nb + c);
  t_lds[r][c + 0] = f2bf(v.x);
  t_lds[r][c + 1] = f2bf(v.y);
  t_lds[r][c + 2] = f2bf(v.z);
  t_lds[r][c + 3] = f2bf(v.w);
  __syncthreads();
  u16x4 o;
  o.x = t_lds[c + 0][r]; o.y = t_lds[c + 1][r];
  o.z = t_lds[c + 2][r]; o.w = t_lds[c + 3][r];
  *reinterpret_cast<u16x4*>(wt + (size_t)(wsel * 1024 + nb + r) * 1024 + kb + c) = o;
}

__global__ __launch_bounds__(256) void pack_bias_kernel(const float* __restrict__ bq,
                                                        const float* __restrict__ bk,
                                                        const float* __restrict__ bv,
                                                        float* __restrict__ bias3) {
  int i = blockIdx.x * 256 + threadIdx.x;
  if (i < 3072) bias3[i] = (i < 1024) ? bq[i] : (i < 2048) ? bk[i - 1024] : bv[i - 2048];
}

// ---------------- GEMM: 2-phase dbuf, single barrier per K-step ----------------
// MODE 0: out-proj, fp32 C (=Cf), N=1024. MODE 1: QKV, N=3072: Q/K -> qk[m][2048]
// (Q scaled by 0.125*log2e), V -> vt[b*16+h][d][s] transposed.
template <int MODE>
__global__ __launch_bounds__(256) void gemm_bt_kernel(const unsigned short* __restrict__ A,
                                                      const unsigned short* __restrict__ Bt,
                                                      const float* __restrict__ bias,
                                                      float* __restrict__ Cf,
                                                      unsigned short* __restrict__ qk,
                                                      unsigned short* __restrict__ vt,
                                                      int N) {
  constexpr int K = 1024;
  __shared__ __align__(16) unsigned short a_lds[2][128 * 32];
  __shared__ __align__(16) unsigned short b_lds[2][128 * 32];
  const int nb = N >> 7;
  const int nwg = nb << 5;
  const int cpx = nwg >> 3;
  const int wg = ((int)blockIdx.x & 7) * cpx + ((int)blockIdx.x >> 3);  // XCD swizzle
  const int bm = wg / nb;
  const int bn = wg % nb;
  const int m0 = bm << 7, n0 = bn << 7;
  const int tid = threadIdx.x;
  const int w = tid >> 6, l = tid & 63;
  const int lr = l & 15, lg = l >> 4;
  const int wm = (w >> 1) << 6, wn = (w & 1) << 6;

  const int q0 = w * 2, q1 = w * 2 + 1;
  const unsigned short* pa0 = A + (size_t)(m0 + q0 * 16 + (l >> 2)) * K + (l & 3) * 8;
  const unsigned short* pa1 = A + (size_t)(m0 + q1 * 16 + (l >> 2)) * K + (l & 3) * 8;
  const unsigned short* pb0 = Bt + (size_t)(n0 + q0 * 16 + (l >> 2)) * K + (l & 3) * 8;
  const unsigned short* pb1 = Bt + (size_t)(n0 + q1 * 16 + (l >> 2)) * K + (l & 3) * 8;

#define GEMM_STAGE(buf, k0)                                                        \
  do {                                                                             \
    __builtin_amdgcn_global_load_lds((const AS1 void*)(pa0 + (k0)),                \
        (AS3 void*)(&a_lds[buf][q0 * 512]), 16, 0, 0);                             \
    __builtin_amdgcn_global_load_lds((const AS1 void*)(pa1 + (k0)),                \
        (AS3 void*)(&a_lds[buf][q1 * 512]), 16, 0, 0);                             \
    __builtin_amdgcn_global_load_lds((const AS1 void*)(pb0 + (k0)),                \
        (AS3 void*)(&b_lds[buf][q0 * 512]), 16, 0, 0);                             \
    __builtin_amdgcn_global_load_lds((const AS1 void*)(pb1 + (k0)),                \
        (AS3 void*)(&b_lds[buf][q1 * 512]), 16, 0, 0);                             \
  } while (0)

  f32x4 acc[4][4] = {};
  GEMM_STAGE(0, 0);
  __syncthreads();

  int cur = 0;
  for (int k0 = 0; k0 < K; k0 += 32) {
    if (k0 + 32 < K) GEMM_STAGE(cur ^ 1, k0 + 32);
    short8 af[4], bfr[4];
#pragma unroll
    for (int i = 0; i < 4; ++i)
      af[i] = *reinterpret_cast<const short8*>(&a_lds[cur][(wm + i * 16 + lr) * 32 + lg * 8]);
#pragma unroll
    for (int i = 0; i < 4; ++i)
      bfr[i] = *reinterpret_cast<const short8*>(&b_lds[cur][(wn + i * 16 + lr) * 32 + lg * 8]);
#pragma unroll
    for (int i = 0; i < 4; ++i)
#pragma unroll
      for (int j = 0; j < 4; ++j)
        acc[i][j] = MFMA16(af[i], bfr[j], acc[i][j]);
    __syncthreads();
    cur ^= 1;
  }
#undef GEMM_STAGE

  if constexpr (MODE == 0) {
#pragma unroll
    for (int i = 0; i < 4; ++i)
#pragma unroll
      for (int j = 0; j < 4; ++j)
#pragma unroll
        for (int r = 0; r < 4; ++r) {
          int m = m0 + wm + i * 16 + lg * 4 + r;
          int n = n0 + wn + j * 16 + lr;
          Cf[(size_t)m * N + n] = acc[i][j][r] + bias[n];
        }
  } else {
    if (n0 < 2048) {
      const float scale = (n0 < 1024) ? 0.18033688011111f : 1.0f;  // Q: 0.125*log2e
#pragma unroll
      for (int i = 0; i < 4; ++i)
#pragma unroll
        for (int j = 0; j < 4; ++j)
#pragma unroll
          for (int r = 0; r < 4; ++r) {
            int m = m0 + wm + i * 16 + lg * 4 + r;
            int n = n0 + wn + j * 16 + lr;
            qk[(size_t)m * 2048 + n] = f2bf((acc[i][j][r] + bias[n]) * scale);
          }
    } else {
      // V -> vt[(b*16+h)][d][s]: transposed store, 4 consecutive s per thread.
#pragma unroll
      for (int i = 0; i < 4; ++i) {
        int m_ = m0 + wm + i * 16 + lg * 4;
        int bb = m_ >> 11, ss = m_ & 2047;
#pragma unroll
        for (int j = 0; j < 4; ++j) {
          int np = n0 - 2048 + wn + j * 16 + lr;
          int hh = np >> 6, dd = np & 63;
          float bv = bias[np + 2048];
          u16x4 pk;
          pk.x = f2bf(acc[i][j][0] + bv);
          pk.y = f2bf(acc[i][j][1] + bv);
          pk.z = f2bf(acc[i][j][2] + bv);
          pk.w = f2bf(acc[i][j][3] + bv);
          *reinterpret_cast<u16x4*>(vt + (size_t)(bb * 16 + hh) * 131072 + dd * 2048 + ss) = pk;
        }
      }
    }
  }
}

// ---------------- flash attention: barrier-free, LDS-free loop ----------------
// grid 2048 = (b,h)[32] x qblocks[64 of 32 rows]; 2 waves; wave w owns KV half
// [w*1024, w*1024+1024), 16 tiles of 64. Fixed-base softmax (p = exp2(s), Q pre-scaled
// into log2 domain) -> partials additive -> LDS merge epilogue only.
__global__ __launch_bounds__(128, 4) void attn_kernel(const unsigned short* __restrict__ qk,
                                                      const unsigned short* __restrict__ vt,
                                                      unsigned short* __restrict__ aout) {
  __shared__ __align__(16) char lds[12544];   // mbuf 8K | dbuf 128B | obuf 4K
  const int tid = threadIdx.x;
  const int w = tid >> 6, l = tid & 63;
  const int lq = l & 31, hi = l >> 5;
  const int wg = ((int)blockIdx.x & 7) * 256 + ((int)blockIdx.x >> 3);  // XCD swizzle
  const int bh = wg >> 6, qb = wg & 63;
  const int b = bh >> 4, h = bh & 15;

  // Q fragments (B-operand): lane holds Q[q=lq][d = c*16 + hi*8 ..+8], pre-scaled.
  short8 qf[4];
  {
    const unsigned short* qrow = qk + (size_t)(b * 2048 + qb * 32 + lq) * 2048 + h * 64 + hi * 8;
#pragma unroll
    for (int c = 0; c < 4; ++c)
      qf[c] = *reinterpret_cast<const short8*>(qrow + c * 16);
  }

  // K fragment base (A-operand): K[t = t0+lq][d = c*16 + hi*8]; row stride 2048 elems.
  const unsigned short* kp =
      qk + (size_t)(b * 2048 + w * 1024 + lq) * 2048 + 1024 + h * 64 + hi * 8;
  // V^T fragment base (A-operand): VT[d = lq][t = t0 + c*16 + hi*8]; row stride 2048.
  const unsigned short* vp = vt + (size_t)bh * 131072 + (size_t)lq * 2048 + w * 1024 + hi * 8;

  float ls0 = 0.f, ls1 = 0.f, ls2 = 0.f, ls3 = 0.f;
  f32x16 ot0 = {}, ot1 = {};

  for (int it = 0; it < 16; ++it) {
    // V^T fragments for this tile (independent of QK -> loads fly under QK+softmax)
    short8 vta[4];
#pragma unroll
    for (int c = 0; c < 4; ++c)
      vta[c] = *reinterpret_cast<const short8*>(vp + c * 16);

    // --- QK^T (swapped): lane owns S^T[.][q=lq] ---
    f32x16 s0 = {}, s1 = {};
    __builtin_amdgcn_s_setprio(1);
#pragma unroll
    for (int c = 0; c < 4; ++c) {
      short8 kf0 = *reinterpret_cast<const short8*>(kp + c * 16);
      short8 kf1 = *reinterpret_cast<const short8*>(kp + 32 * 2048 + c * 16);
      s0 = MFMA32(kf0, qf[c], s0);
      s1 = MFMA32(kf1, qf[c], s1);
    }
    __builtin_amdgcn_s_setprio(0);

    // --- softmax-lite: p = exp2(s); persistent partial sums ---
    float p0[16], p1[16];
#pragma unroll
    for (int i = 0; i < 16; ++i) {
      p0[i] = __builtin_exp2f(s0[i]);
      if ((i & 3) == 0) ls0 += p0[i]; else if ((i & 3) == 1) ls1 += p0[i];
      else if ((i & 3) == 2) ls2 += p0[i]; else ls3 += p0[i];
    }
#pragma unroll
    for (int i = 0; i < 16; ++i) {
      p1[i] = __builtin_exp2f(s1[i]);
      if ((i & 3) == 0) ls0 += p1[i]; else if ((i & 3) == 1) ls1 += p1[i];
      else if ((i & 3) == 2) ls2 += p1[i]; else ls3 += p1[i];
    }

    // --- P -> bf16 B-fragments (cvt_pk + permlane32_swap) ---
    short8 pf[4];
    {
      unsigned a0 = cvt_pk_bf16(p0[0], p0[1]),   a1 = cvt_pk_bf16(p0[4], p0[5]);
      unsigned b0 = cvt_pk_bf16(p0[2], p0[3]),   b1 = cvt_pk_bf16(p0[6], p0[7]);
      pl32_swap(a0, a1); pl32_swap(b0, b1);
      pf[0] = mk8(a0, b0, a1, b1);
      unsigned c0 = cvt_pk_bf16(p0[8], p0[9]),   c1 = cvt_pk_bf16(p0[12], p0[13]);
      unsigned d0 = cvt_pk_bf16(p0[10], p0[11]), d1 = cvt_pk_bf16(p0[14], p0[15]);
      pl32_swap(c0, c1); pl32_swap(d0, d1);
      pf[1] = mk8(c0, d0, c1, d1);
      unsigned e0 = cvt_pk_bf16(p1[0], p1[1]),   e1 = cvt_pk_bf16(p1[4], p1[5]);
      unsigned f0 = cvt_pk_bf16(p1[2], p1[3]),   f1 = cvt_pk_bf16(p1[6], p1[7]);
      pl32_swap(e0, e1); pl32_swap(f0, f1);
      pf[2] = mk8(e0, f0, e1, f1);
      unsigned g0 = cvt_pk_bf16(p1[8], p1[9]),   g1 = cvt_pk_bf16(p1[12], p1[13]);
      unsigned h0 = cvt_pk_bf16(p1[10], p1[11]), h1 = cvt_pk_bf16(p1[14], p1[15]);
      pl32_swap(g0, g1); pl32_swap(h0, h1);
      pf[3] = mk8(g0, h0, g1, h1);
    }

    // --- PV (transposed): ot[dblk] += mfma(V^T frag, P frag) ---
    __builtin_amdgcn_s_setprio(1);
#pragma unroll
    for (int c = 0; c < 4; ++c) {
      short8 vtb = *reinterpret_cast<const short8*>(vp + 32 * 2048 + c * 16);
      ot0 = MFMA32(vta[c], pf[c], ot0);
      ot1 = MFMA32(vtb, pf[c], ot1);
    }
    __builtin_amdgcn_s_setprio(0);

    kp += 64 * 2048;   // next 64 K rows
    vp += 64;          // next 64 t columns
  }

  // ---- merge epilogue: O = O_w0 + O_w1, l = l_w0 + l_w1 (fixed-base -> additive) ----
  float* mbuf = (float*)lds;               // [64 d][32 q] fp32
  float* dbuf = (float*)(lds + 8192);      // [32 q]
  char*  obuf = lds + 8320;                // [32 q][64 d] bf16, q-row swizzled

  float lsum = (ls0 + ls1) + (ls2 + ls3);
  lsum += __shfl_xor(lsum, 32, 64);        // combine hi halves of this wave

  if (w == 1) {
#pragma unroll
    for (int r = 0; r < 16; ++r) {
      int d = (r & 3) + 8 * (r >> 2) + 4 * hi;
      mbuf[d * 32 + lq] = ot0[r];
      mbuf[(32 + d) * 32 + lq] = ot1[r];
    }
    if (hi == 0) dbuf[lq] = lsum;
  }
  __syncthreads();
  if (w == 0) {
    const float inv = 1.0f / (lsum + dbuf[lq]);
    const int swz = (lq & 7) << 4;
#pragma unroll
    for (int r = 0; r < 16; r += 2) {
      int d = (r & 3) + 8 * (r >> 2) + 4 * hi;   // r even: regs r,r+1 -> d,d+1
      float o0a = (ot0[r] + mbuf[d * 32 + lq]) * inv;
      float o0b = (ot0[r + 1] + mbuf[(d + 1) * 32 + lq]) * inv;
      *(unsigned*)(obuf + lq * 128 + ((2 * d) ^ swz)) = cvt_pk_bf16(o0a, o0b);
      float o1a = (ot1[r] + mbuf[(32 + d) * 32 + lq]) * inv;
      float o1b = (ot1[r + 1] + mbuf[(33 + d) * 32 + lq]) * inv;
      *(unsigned*)(obuf + lq * 128 + ((2 * (32 + d)) ^ swz)) = cvt_pk_bf16(o1a, o1b);
    }
  }
  __syncthreads();
  // coalesced store: 128 threads cover 32 rows x 128 B
  {
    int row = tid >> 2;
    int c2 = (tid & 3) * 2;
    int swzr = (row & 7) << 4;
    const char* src = obuf + row * 128;
    short8 v0 = *reinterpret_cast<const short8*>(src + ((c2 * 16) ^ swzr));
    short8 v1 = *reinterpret_cast<const short8*>(src + (((c2 + 1) * 16) ^ swzr));
    unsigned short* orow = aout + (size_t)(b * 2048 + qb * 32 + row) * 1024 + h * 64 + c2 * 8;
    *reinterpret_cast<short8*>(orow) = v0;
    *reinterpret_cast<short8*>(orow + 8) = v1;
  }
}

// ---------------- host ----------------
extern "C" void kernel_launch(void* const* d_in, const int* in_sizes, int n_in,
                              void* d_out, int out_size, void* d_ws, size_t ws_size,
                              hipStream_t stream) {
  const float* x  = (const float*)d_in[0];
  const float* wq = (const float*)d_in[1];
  const float* bq = (const float*)d_in[2];
  const float* wk = (const float*)d_in[3];
  const float* bk = (const float*)d_in[4];
  const float* wv = (const float*)d_in[5];
  const float* bv = (const float*)d_in[6];
  const float* wo = (const float*)d_in[7];
  const float* bo = (const float*)d_in[8];
  float* out = (float*)d_out;

  char* ws = (char*)d_ws;
  unsigned short* xb    = (unsigned short*)(ws);                     // 8 MiB (dead after QKV)
  unsigned short* aob   = (unsigned short*)(ws);                     // reuse region 0
  unsigned short* wt    = (unsigned short*)(ws + 8388608);           // 8 MiB
  float*          bias3 = (float*)(ws + 16777216);                   // 12 KiB
  unsigned short* qkb   = (unsigned short*)(ws + 16777216 + 16384);  // 16 MiB Q|K [4096][2048]
  unsigned short* vtb   = (unsigned short*)(ws + 33554432 + 16384);  // 8 MiB V^T [32][64][2048]

  cast_x_kernel<<<4096, 256, 0, stream>>>(x, xb);
  prep_w_kernel<<<4096, 256, 0, stream>>>(wq, wk, wv, wo, wt);
  pack_bias_kernel<<<12, 256, 0, stream>>>(bq, bk, bv, bias3);

  // fused QKV projection: Q/K -> qkb (Q pre-scaled by 0.125*log2e), V -> vtb transposed
  gemm_bt_kernel<1><<<768, 256, 0, stream>>>(xb, wt, bias3, nullptr, qkb, vtb, 3072);

  // attention -> aob [4096][1024] bf16
  attn_kernel<<<2048, 128, 0, stream>>>(qkb, vtb, aob);

  // output projection -> fp32 d_out [4096][1024]
  gemm_bt_kernel<0><<<256, 256, 0, stream>>>(aob, wt + (size_t)3072 * 1024, bo, out,
                                             nullptr, nullptr, 1024);
}

// Round 7
// 174.750 us; speedup vs baseline: 1.2451x; 1.2451x over previous
//
#include <hip/hip_runtime.h>
#include <stdint.h>
#include <stddef.h>

// MHA: x[2,2048,1024] -> QKV proj (bf16 MFMA) -> flash attn (H=16, Dh=64) -> out proj.
// R7: R6 structure with the tile-count fix (32 tiles of 32 t per 1024-key wave-half;
//     R6 ran only 16 -> dropped half the keys). attn = 2-wave/128-thr blocks, in-block
//     KV split (additive fixed-base partials), K via global_load_lds (pre-swizzled src)
//     into per-wave private dbuf, barrier-free counted-vmcnt loop, V^T direct from L2.

typedef __attribute__((ext_vector_type(8))) short short8;
typedef __attribute__((ext_vector_type(4))) float f32x4;
typedef __attribute__((ext_vector_type(16))) float f32x16;
typedef __attribute__((ext_vector_type(4))) unsigned short u16x4;

#define MFMA16(a, b, c) __builtin_amdgcn_mfma_f32_16x16x32_bf16((a), (b), (c), 0, 0, 0)
#define MFMA32(a, b, c) __builtin_amdgcn_mfma_f32_32x32x16_bf16((a), (b), (c), 0, 0, 0)
#define AS1 __attribute__((address_space(1)))
#define AS3 __attribute__((address_space(3)))

__device__ __forceinline__ unsigned short f2bf(float f) {
  union { float f; unsigned u; } v; v.f = f;
  unsigned r = v.u + 0x7fffu + ((v.u >> 16) & 1u);   // RNE
  return (unsigned short)(r >> 16);
}

__device__ __forceinline__ unsigned cvt_pk_bf16(float lo, float hi) {
  unsigned r;
  asm("v_cvt_pk_bf16_f32 %0, %1, %2" : "=v"(r) : "v"(lo), "v"(hi));
  return r;
}

__device__ __forceinline__ void pl32_swap(unsigned& a, unsigned& b) {
  asm volatile("v_permlane32_swap_b32 %0, %1" : "+v"(a), "+v"(b));
}

__device__ __forceinline__ short8 mk8(unsigned a, unsigned b, unsigned c, unsigned d) {
  union { unsigned u[4]; short8 s; } v;
  v.u[0] = a; v.u[1] = b; v.u[2] = c; v.u[3] = d;
  return v.s;
}

// ---------------- prep ----------------
__global__ __launch_bounds__(256) void cast_x_kernel(const float* __restrict__ x,
                                                     unsigned short* __restrict__ xb) {
  int i = (blockIdx.x * 256 + threadIdx.x) * 4;
  float4 v = *reinterpret_cast<const float4*>(x + i);
  u16x4 o;
  o.x = f2bf(v.x); o.y = f2bf(v.y); o.z = f2bf(v.z); o.w = f2bf(v.w);
  *reinterpret_cast<u16x4*>(xb + i) = o;
}

__global__ __launch_bounds__(256) void prep_w_kernel(const float* __restrict__ wq,
                                                     const float* __restrict__ wk,
                                                     const float* __restrict__ wv,
                                                     const float* __restrict__ wo,
                                                     unsigned short* __restrict__ wt) {
  __shared__ unsigned short t_lds[32][33];
  int bid = blockIdx.x;
  int wsel = bid >> 10;
  int rem = bid & 1023;
  int kb = (rem >> 5) << 5;
  int nb = (rem & 31) << 5;
  const float* W = (wsel == 0) ? wq : (wsel == 1) ? wk : (wsel == 2) ? wv : wo;
  int t = threadIdx.x;
  int r = t >> 3, c = (t & 7) * 4;
  float4 v = *reinterpret_cast<const float4*>(W + (size_t)(kb + r) * 1024 + nb + c);
  t_lds[r][c + 0] = f2bf(v.x);
  t_lds[r][c + 1] = f2bf(v.y);
  t_lds[r][c + 2] = f2bf(v.z);
  t_lds[r][c + 3] = f2bf(v.w);
  __syncthreads();
  u16x4 o;
  o.x = t_lds[c + 0][r]; o.y = t_lds[c + 1][r];
  o.z = t_lds[c + 2][r]; o.w = t_lds[c + 3][r];
  *reinterpret_cast<u16x4*>(wt + (size_t)(wsel * 1024 + nb + r) * 1024 + kb + c) = o;
}

__global__ __launch_bounds__(256) void pack_bias_kernel(const float* __restrict__ bq,
                                                        const float* __restrict__ bk,
                                                        const float* __restrict__ bv,
                                                        float* __restrict__ bias3) {
  int i = blockIdx.x * 256 + threadIdx.x;
  if (i < 3072) bias3[i] = (i < 1024) ? bq[i] : (i < 2048) ? bk[i - 1024] : bv[i - 2048];
}

// ---------------- GEMM: 2-phase dbuf, single barrier per K-step ----------------
// MODE 0: out-proj, fp32 C (=Cf), N=1024. MODE 1: QKV, N=3072: Q/K -> qk[m][2048]
// (Q scaled by 0.125*log2e), V -> vt[b*16+h][d][s] transposed.
template <int MODE>
__global__ __launch_bounds__(256) void gemm_bt_kernel(const unsigned short* __restrict__ A,
                                                      const unsigned short* __restrict__ Bt,
                                                      const float* __restrict__ bias,
                                                      float* __restrict__ Cf,
                                                      unsigned short* __restrict__ qk,
                                                      unsigned short* __restrict__ vt,
                                                      int N) {
  constexpr int K = 1024;
  __shared__ __align__(16) unsigned short a_lds[2][128 * 32];
  __shared__ __align__(16) unsigned short b_lds[2][128 * 32];
  const int nb = N >> 7;
  const int nwg = nb << 5;
  const int cpx = nwg >> 3;
  const int wg = ((int)blockIdx.x & 7) * cpx + ((int)blockIdx.x >> 3);  // XCD swizzle
  const int bm = wg / nb;
  const int bn = wg % nb;
  const int m0 = bm << 7, n0 = bn << 7;
  const int tid = threadIdx.x;
  const int w = tid >> 6, l = tid & 63;
  const int lr = l & 15, lg = l >> 4;
  const int wm = (w >> 1) << 6, wn = (w & 1) << 6;

  const int q0 = w * 2, q1 = w * 2 + 1;
  const unsigned short* pa0 = A + (size_t)(m0 + q0 * 16 + (l >> 2)) * K + (l & 3) * 8;
  const unsigned short* pa1 = A + (size_t)(m0 + q1 * 16 + (l >> 2)) * K + (l & 3) * 8;
  const unsigned short* pb0 = Bt + (size_t)(n0 + q0 * 16 + (l >> 2)) * K + (l & 3) * 8;
  const unsigned short* pb1 = Bt + (size_t)(n0 + q1 * 16 + (l >> 2)) * K + (l & 3) * 8;

#define GEMM_STAGE(buf, k0)                                                        \
  do {                                                                             \
    __builtin_amdgcn_global_load_lds((const AS1 void*)(pa0 + (k0)),                \
        (AS3 void*)(&a_lds[buf][q0 * 512]), 16, 0, 0);                             \
    __builtin_amdgcn_global_load_lds((const AS1 void*)(pa1 + (k0)),                \
        (AS3 void*)(&a_lds[buf][q1 * 512]), 16, 0, 0);                             \
    __builtin_amdgcn_global_load_lds((const AS1 void*)(pb0 + (k0)),                \
        (AS3 void*)(&b_lds[buf][q0 * 512]), 16, 0, 0);                             \
    __builtin_amdgcn_global_load_lds((const AS1 void*)(pb1 + (k0)),                \
        (AS3 void*)(&b_lds[buf][q1 * 512]), 16, 0, 0);                             \
  } while (0)

  f32x4 acc[4][4] = {};
  GEMM_STAGE(0, 0);
  __syncthreads();

  int cur = 0;
  for (int k0 = 0; k0 < K; k0 += 32) {
    if (k0 + 32 < K) GEMM_STAGE(cur ^ 1, k0 + 32);
    short8 af[4], bfr[4];
#pragma unroll
    for (int i = 0; i < 4; ++i)
      af[i] = *reinterpret_cast<const short8*>(&a_lds[cur][(wm + i * 16 + lr) * 32 + lg * 8]);
#pragma unroll
    for (int i = 0; i < 4; ++i)
      bfr[i] = *reinterpret_cast<const short8*>(&b_lds[cur][(wn + i * 16 + lr) * 32 + lg * 8]);
#pragma unroll
    for (int i = 0; i < 4; ++i)
#pragma unroll
      for (int j = 0; j < 4; ++j)
        acc[i][j] = MFMA16(af[i], bfr[j], acc[i][j]);
    __syncthreads();
    cur ^= 1;
  }
#undef GEMM_STAGE

  if constexpr (MODE == 0) {
#pragma unroll
    for (int i = 0; i < 4; ++i)
#pragma unroll
      for (int j = 0; j < 4; ++j)
#pragma unroll
        for (int r = 0; r < 4; ++r) {
          int m = m0 + wm + i * 16 + lg * 4 + r;
          int n = n0 + wn + j * 16 + lr;
          Cf[(size_t)m * N + n] = acc[i][j][r] + bias[n];
        }
  } else {
    if (n0 < 2048) {
      const float scale = (n0 < 1024) ? 0.18033688011111f : 1.0f;  // Q: 0.125*log2e
#pragma unroll
      for (int i = 0; i < 4; ++i)
#pragma unroll
        for (int j = 0; j < 4; ++j)
#pragma unroll
          for (int r = 0; r < 4; ++r) {
            int m = m0 + wm + i * 16 + lg * 4 + r;
            int n = n0 + wn + j * 16 + lr;
            qk[(size_t)m * 2048 + n] = f2bf((acc[i][j][r] + bias[n]) * scale);
          }
    } else {
      // V -> vt[(b*16+h)][d][s]: transposed store, 4 consecutive s per thread.
#pragma unroll
      for (int i = 0; i < 4; ++i) {
        int m_ = m0 + wm + i * 16 + lg * 4;
        int bb = m_ >> 11, ss = m_ & 2047;
#pragma unroll
        for (int j = 0; j < 4; ++j) {
          int np = n0 - 2048 + wn + j * 16 + lr;
          int hh = np >> 6, dd = np & 63;
          float bv = bias[np + 2048];
          u16x4 pk;
          pk.x = f2bf(acc[i][j][0] + bv);
          pk.y = f2bf(acc[i][j][1] + bv);
          pk.z = f2bf(acc[i][j][2] + bv);
          pk.w = f2bf(acc[i][j][3] + bv);
          *reinterpret_cast<u16x4*>(vt + (size_t)(bb * 16 + hh) * 131072 + dd * 2048 + ss) = pk;
        }
      }
    }
  }
}

// ---------------- flash attention ----------------
// grid 2048 = (b,h)[32] x qblocks[64 of 32 rows]; 2 waves of 64; wave w owns KV half
// [w*1024, w*1024+1024) in 32 tiles of 32 t. Fixed-base softmax -> additive partials,
// merged in the epilogue via LDS. K: global_load_lds into per-wave private dbuf
// (pre-swizzled source; zero loop barriers; counted vmcnt). V^T frags direct global.
__global__ __launch_bounds__(128, 4) void attn_kernel(const unsigned short* __restrict__ qk,
                                                      const unsigned short* __restrict__ vt,
                                                      unsigned short* __restrict__ aout) {
  __shared__ __align__(16) char lds[16384];   // [wave0 K dbuf 8K][wave1 K dbuf 8K]
  const int tid = threadIdx.x;
  const int w = tid >> 6, l = tid & 63;
  const int lq = l & 31, hi = l >> 5;
  const int wg = ((int)blockIdx.x & 7) * 256 + ((int)blockIdx.x >> 3);  // XCD swizzle
  const int bh = wg >> 6, qb = wg & 63;
  const int b = bh >> 4, h = bh & 15;

  // Q fragments (B-operand), pre-scaled by 0.125*log2e in the GEMM epilogue.
  short8 qf[4];
  {
    const unsigned short* qrow = qk + (size_t)(b * 2048 + qb * 32 + lq) * 2048 + h * 64 + hi * 8;
#pragma unroll
    for (int c = 0; c < 4; ++c)
      qf[c] = *reinterpret_cast<const short8*>(qrow + c * 16);
  }

  // K staging sources (pre-swizzled: LDS linear <- src col XOR'd). Plane = [32 t][128 B],
  // swizzle (t&7)<<4; gll chunk j covers rows j*8..j*8+7; lane row bits = l>>3 (== t&7).
  const int tloc = l >> 3;
  const int colsw = (16 * (l & 7)) ^ (tloc << 4);
  const char* kq = (const char*)qk +
                   (((size_t)(b * 2048 + w * 1024) * 2048 + 1024 + h * 64) << 1);
  const char* ks0 = kq + (size_t)tloc * 4096 + colsw;
  const char* ks1 = ks0 + 32768;
  const char* ks2 = ks0 + 65536;
  const char* ks3 = ks0 + 98304;

  // V^T fragment bases (direct global): vt[bh][d][2048 t].
  const unsigned short* vs0 = vt + (size_t)bh * 131072 + (size_t)lq * 2048 + w * 1024 + hi * 8;
  const unsigned short* vs1 = vs0 + 32 * 2048;   // d-block 1

  // loop-invariant LDS offsets
  const int kreg = w * 8192;
  int aoff[4];
#pragma unroll
  for (int c = 0; c < 4; ++c)
    aoff[c] = kreg + lq * 128 + ((c * 32 + hi * 16) ^ ((lq & 7) << 4));

  float ls0 = 0.f, ls1 = 0.f, ls2 = 0.f, ls3 = 0.f;
  f32x16 ot0 = {}, ot1 = {};

  // prologue: stage K tile 0 into buf 0
  __builtin_amdgcn_global_load_lds((const AS1 void*)ks0, (AS3 void*)(lds + kreg), 16, 0, 0);
  __builtin_amdgcn_global_load_lds((const AS1 void*)ks1, (AS3 void*)(lds + kreg + 1024), 16, 0, 0);
  __builtin_amdgcn_global_load_lds((const AS1 void*)ks2, (AS3 void*)(lds + kreg + 2048), 16, 0, 0);
  __builtin_amdgcn_global_load_lds((const AS1 void*)ks3, (AS3 void*)(lds + kreg + 3072), 16, 0, 0);
  ks0 += 131072; ks1 += 131072; ks2 += 131072; ks3 += 131072;

  int cur = 0;
  // VMK: wait K(i) staged (newer in flight: 4 V + [4 gll]); VMV: wait V(i) (newer: [4 gll])
#define ATTN_TILE(MORE, WAITK, WAITV)                                                  \
  {                                                                                    \
    /* V(i) fragment loads first (oldest of this iter's group) */                      \
    short8 vf0 = *reinterpret_cast<const short8*>(vs0);                                \
    short8 vf1 = *reinterpret_cast<const short8*>(vs0 + 16);                           \
    short8 vf2 = *reinterpret_cast<const short8*>(vs1);                                \
    short8 vf3 = *reinterpret_cast<const short8*>(vs1 + 16);                           \
    __builtin_amdgcn_sched_barrier(0);  /* pin: V loads before gll */                  \
    if (MORE) {                                                                        \
      const int nb_ = kreg + ((cur ^ 1) << 12);                                        \
      __builtin_amdgcn_global_load_lds((const AS1 void*)ks0, (AS3 void*)(lds + nb_), 16, 0, 0); \
      __builtin_amdgcn_global_load_lds((const AS1 void*)ks1, (AS3 void*)(lds + nb_ + 1024), 16, 0, 0); \
      __builtin_amdgcn_global_load_lds((const AS1 void*)ks2, (AS3 void*)(lds + nb_ + 2048), 16, 0, 0); \
      __builtin_amdgcn_global_load_lds((const AS1 void*)ks3, (AS3 void*)(lds + nb_ + 3072), 16, 0, 0); \
      ks0 += 131072; ks1 += 131072; ks2 += 131072; ks3 += 131072;                      \
    }                                                                                  \
    asm volatile("s_waitcnt vmcnt(" WAITK ")" ::: "memory");                           \
    __builtin_amdgcn_sched_barrier(0);                                                 \
    const int bofs = cur << 12;                                                        \
    f32x16 s = {};                                                                     \
    __builtin_amdgcn_s_setprio(1);                                                     \
    s = MFMA32(*reinterpret_cast<const short8*>(lds + aoff[0] + bofs), qf[0], s);      \
    s = MFMA32(*reinterpret_cast<const short8*>(lds + aoff[1] + bofs), qf[1], s);      \
    s = MFMA32(*reinterpret_cast<const short8*>(lds + aoff[2] + bofs), qf[2], s);      \
    s = MFMA32(*reinterpret_cast<const short8*>(lds + aoff[3] + bofs), qf[3], s);      \
    __builtin_amdgcn_s_setprio(0);                                                     \
    float p[16];                                                                       \
    _Pragma("unroll")                                                                  \
    for (int i_ = 0; i_ < 16; ++i_) {                                                  \
      p[i_] = __builtin_exp2f(s[i_]);                                                  \
      if ((i_ & 3) == 0) ls0 += p[i_]; else if ((i_ & 3) == 1) ls1 += p[i_];           \
      else if ((i_ & 3) == 2) ls2 += p[i_]; else ls3 += p[i_];                         \
    }                                                                                  \
    unsigned a0 = cvt_pk_bf16(p[0], p[1]),   a1 = cvt_pk_bf16(p[4], p[5]);             \
    unsigned b0 = cvt_pk_bf16(p[2], p[3]),   b1 = cvt_pk_bf16(p[6], p[7]);             \
    pl32_swap(a0, a1); pl32_swap(b0, b1);                                              \
    short8 pf0 = mk8(a0, b0, a1, b1);                                                  \
    unsigned c0 = cvt_pk_bf16(p[8], p[9]),   c1 = cvt_pk_bf16(p[12], p[13]);           \
    unsigned d0 = cvt_pk_bf16(p[10], p[11]), d1 = cvt_pk_bf16(p[14], p[15]);           \
    pl32_swap(c0, c1); pl32_swap(d0, d1);                                              \
    short8 pf1 = mk8(c0, d0, c1, d1);                                                  \
    asm volatile("s_waitcnt vmcnt(" WAITV ")" ::: "memory");                           \
    __builtin_amdgcn_sched_barrier(0);                                                 \
    __builtin_amdgcn_s_setprio(1);                                                     \
    ot0 = MFMA32(vf0, pf0, ot0);                                                       \
    ot0 = MFMA32(vf1, pf1, ot0);                                                       \
    ot1 = MFMA32(vf2, pf0, ot1);                                                       \
    ot1 = MFMA32(vf3, pf1, ot1);                                                       \
    __builtin_amdgcn_s_setprio(0);                                                     \
    vs0 += 32; vs1 += 32;                                                              \
    cur ^= 1;                                                                          \
  }

  for (int it = 0; it < 31; ++it) ATTN_TILE(1, "8", "4");   // 31 steady + 1 final = 32 tiles
  ATTN_TILE(0, "4", "0");
#undef ATTN_TILE

  // ---- merge epilogue: O = O_w0 + O_w1, l = l_w0 + l_w1 (fixed-base -> additive) ----
  float* mbuf = (float*)lds;               // [64 d][32 q] fp32 (8 KiB)
  float* dbuf = (float*)(lds + 8192);      // [32 q]
  char*  obuf = lds + 8320;                // [32 q][64 d] bf16, q-row swizzled

  float lsum = (ls0 + ls1) + (ls2 + ls3);
  lsum += __shfl_xor(lsum, 32, 64);

  __syncthreads();   // both waves done with K bufs
  if (w == 1) {
#pragma unroll
    for (int r = 0; r < 16; ++r) {
      int d = (r & 3) + 8 * (r >> 2) + 4 * hi;
      mbuf[d * 32 + lq] = ot0[r];
      mbuf[(32 + d) * 32 + lq] = ot1[r];
    }
    if (hi == 0) dbuf[lq] = lsum;
  }
  __syncthreads();
  if (w == 0) {
    const float inv = 1.0f / (lsum + dbuf[lq]);
    const int swz = (lq & 7) << 4;
#pragma unroll
    for (int r = 0; r < 16; r += 2) {
      int d = (r & 3) + 8 * (r >> 2) + 4 * hi;
      float o0a = (ot0[r] + mbuf[d * 32 + lq]) * inv;
      float o0b = (ot0[r + 1] + mbuf[(d + 1) * 32 + lq]) * inv;
      *(unsigned*)(obuf + lq * 128 + ((2 * d) ^ swz)) = cvt_pk_bf16(o0a, o0b);
      float o1a = (ot1[r] + mbuf[(32 + d) * 32 + lq]) * inv;
      float o1b = (ot1[r + 1] + mbuf[(33 + d) * 32 + lq]) * inv;
      *(unsigned*)(obuf + lq * 128 + ((2 * (32 + d)) ^ swz)) = cvt_pk_bf16(o1a, o1b);
    }
  }
  __syncthreads();
  // coalesced store: 128 threads cover 32 rows x 128 B
  {
    int row = tid >> 2;
    int c2 = (tid & 3) * 2;
    int swzr = (row & 7) << 4;
    const char* src = obuf + row * 128;
    short8 v0 = *reinterpret_cast<const short8*>(src + ((c2 * 16) ^ swzr));
    short8 v1 = *reinterpret_cast<const short8*>(src + (((c2 + 1) * 16) ^ swzr));
    unsigned short* orow = aout + (size_t)(b * 2048 + qb * 32 + row) * 1024 + h * 64 + c2 * 8;
    *reinterpret_cast<short8*>(orow) = v0;
    *reinterpret_cast<short8*>(orow + 8) = v1;
  }
}

// ---------------- host ----------------
extern "C" void kernel_launch(void* const* d_in, const int* in_sizes, int n_in,
                              void* d_out, int out_size, void* d_ws, size_t ws_size,
                              hipStream_t stream) {
  const float* x  = (const float*)d_in[0];
  const float* wq = (const float*)d_in[1];
  const float* bq = (const float*)d_in[2];
  const float* wk = (const float*)d_in[3];
  const float* bk = (const float*)d_in[4];
  const float* wv = (const float*)d_in[5];
  const float* bv = (const float*)d_in[6];
  const float* wo = (const float*)d_in[7];
  const float* bo = (const float*)d_in[8];
  float* out = (float*)d_out;

  char* ws = (char*)d_ws;
  unsigned short* xb    = (unsigned short*)(ws);                     // 8 MiB (dead after QKV)
  unsigned short* aob   = (unsigned short*)(ws);                     // reuse region 0
  unsigned short* wt    = (unsigned short*)(ws + 8388608);           // 8 MiB
  float*          bias3 = (float*)(ws + 16777216);                   // 12 KiB
  unsigned short* qkb   = (unsigned short*)(ws + 16777216 + 16384);  // 16 MiB Q|K [4096][2048]
  unsigned short* vtb   = (unsigned short*)(ws + 33554432 + 16384);  // 8 MiB V^T [32][64][2048]

  cast_x_kernel<<<4096, 256, 0, stream>>>(x, xb);
  prep_w_kernel<<<4096, 256, 0, stream>>>(wq, wk, wv, wo, wt);
  pack_bias_kernel<<<12, 256, 0, stream>>>(bq, bk, bv, bias3);

  // fused QKV projection: Q/K -> qkb (Q pre-scaled by 0.125*log2e), V -> vtb transposed
  gemm_bt_kernel<1><<<768, 256, 0, stream>>>(xb, wt, bias3, nullptr, qkb, vtb, 3072);

  // attention -> aob [4096][1024] bf16
  attn_kernel<<<2048, 128, 0, stream>>>(qkb, vtb, aob);

  // output projection -> fp32 d_out [4096][1024]
  gemm_bt_kernel<0><<<256, 256, 0, stream>>>(aob, wt + (size_t)3072 * 1024, bo, out,
                                             nullptr, nullptr, 1024);
}